// Round 1
// 468.851 us; speedup vs baseline: 1.0848x; 1.0848x over previous
//
#include <hip/hip_runtime.h>
#include <hip/hip_bf16.h>
#include <cstdint>

// B=32,C=32,V=1024,L=13; 3 supports x order 2; C_IN=224, C_OUT=64.
//  Arena (d_out): block0 = x-T [n2,v] bf16; block1 = Abf (3x1M bf16);
//                 block2 = AT2 (3x1M bf16). All dead before k_fc writes y.
//  Ht (ws): [m=(b*1024+v)*13+l, cc=224] bf16
//  Hop restructure: h2 = A^2 x. AT2 = AT*A via the same GEMM kernel, then
//  ONE 6-z GEMM launch (z<3: AT, cc=32+64z; z>=3: AT2, cc=64(z-2)) reads x-T.
//  k_fc: A streamed global->VGPR (zero reuse => no LDS staging), W-only LDS,
//        per-wave-independent K-loop, 1-deep prefetch.

#define SZE 13631488ull        // elems per [13312,1024] block
#define OFF_AT  190840832ull   // Ht bytes = 425984*224*2
#define OFF_WB  197132288ull   // OFF_AT + 3*1024*1024*2
#define WS_NEED 197160960ull   // OFF_WB + 64*224*2

typedef __attribute__((ext_vector_type(8))) short short8;
typedef __attribute__((ext_vector_type(4))) float f32x4;

__device__ __forceinline__ unsigned short f2b(float f) {
    unsigned int u = __builtin_bit_cast(unsigned int, f);
    u += 0x7FFFu + ((u >> 16) & 1u);          // round-to-nearest-even
    return (unsigned short)(u >> 16);
}

__device__ __forceinline__ void gl2lds16(const unsigned short* g, unsigned short* l) {
    __builtin_amdgcn_global_load_lds(
        (__attribute__((address_space(1))) void*)(g),
        (__attribute__((address_space(3))) void*)(l), 16, 0, 0);
}

// ---------- fused prep: x[b,c,v,l] f32 -> T rows (block0) + Ht cc0..31 ----------
__global__ __launch_bounds__(256) void k_prep(const float* __restrict__ x,
                                              unsigned short* __restrict__ T,
                                              unsigned short* __restrict__ Ht) {
    __shared__ unsigned short sb[32 * 840];   // [c][e=v*13+l], 832 padded to 840
    const int b = blockIdx.x >> 4, vc = blockIdx.x & 15;
    const int t = threadIdx.x;
    const float4* xb = (const float4*)x;
    for (int it = 0; it < 26; ++it) {
        int q = it * 256 + t;                 // 6656 = 32c * 208f4
        int c = q / 208, f = q - c * 208;
        float4 u = xb[(size_t)(b * 32 + c) * 3328 + vc * 208 + f];
        ushort4 pk; pk.x = f2b(u.x); pk.y = f2b(u.y); pk.z = f2b(u.z); pk.w = f2b(u.w);
        *(ushort4*)(sb + c * 840 + f * 4) = pk;
    }
    __syncthreads();
    unsigned short* Tb = T + (size_t)b * 13 * 32 * 1024 + (size_t)vc * 64;
    for (int it = 0; it < 26; ++it) {
        int q = it * 256 + t;                 // 6656 = 13l * 32c * 16sg
        int l = q >> 9, r = q & 511, c = r >> 4, sg = r & 15;
        const unsigned short* src = sb + c * 840 + l;
        ushort4 pk;
        pk.x = src[(sg * 4 + 0) * 13];
        pk.y = src[(sg * 4 + 1) * 13];
        pk.z = src[(sg * 4 + 2) * 13];
        pk.w = src[(sg * 4 + 3) * 13];
        *(ushort4*)(Tb + (size_t)(l * 32 + c) * 1024 + sg * 4) = pk;
    }
    unsigned short* Hb = Ht + ((size_t)b * 13312 + (size_t)vc * 832) * 224;
    for (int it = 0; it < 26; ++it) {
        int q = it * 256 + t;                 // 6656 = 64v * 13l * 8cs
        int v = q / 104, r = q - v * 104, l = r >> 3, cs = r & 7;
        const unsigned short* src = sb + v * 13 + l;
        ushort4 pk;
        pk.x = src[(cs * 4 + 0) * 840];
        pk.y = src[(cs * 4 + 1) * 840];
        pk.z = src[(cs * 4 + 2) * 840];
        pk.w = src[(cs * 4 + 3) * 840];
        *(ushort4*)(Hb + (size_t)(v * 13 + l) * 224 + cs * 4) = pk;
    }
}

// ---------- prep A: A[v,w] f32 -> AT[w,v] bf16 + Abf[v,w] bf16, 3 mats ----------
__global__ __launch_bounds__(256) void k_prep_A(const float* __restrict__ A0,
                                                const float* __restrict__ A1,
                                                const float* __restrict__ A2,
                                                unsigned short* __restrict__ AT,
                                                unsigned short* __restrict__ Abf) {
    const float* A = blockIdx.z == 0 ? A0 : blockIdx.z == 1 ? A1 : A2;
    unsigned short* D = AT + (size_t)blockIdx.z * 1024 * 1024;
    unsigned short* D2 = Abf + (size_t)blockIdx.z * 1024 * 1024;
    __shared__ float tile[32][33];
    int v0 = blockIdx.y * 32, w0 = blockIdx.x * 32;
    int c = threadIdx.x & 31, r = threadIdx.x >> 5;
    for (int p = 0; p < 4; ++p) {
        int rr = r + p * 8;
        float val = A[(size_t)(v0 + rr) * 1024 + w0 + c];
        tile[rr][c] = val;
        D2[(size_t)(v0 + rr) * 1024 + w0 + c] = f2b(val);
    }
    __syncthreads();
    for (int p = 0; p < 4; ++p) {
        int rr = r + p * 8;
        D[(size_t)(w0 + rr) * 1024 + v0 + c] = f2b(tile[c][rr]);
    }
}

// ---------- prep W: W[o,cc] f32 -> Wb[o,cc] bf16 ----------
__global__ __launch_bounds__(256) void k_prep_W(const float* __restrict__ W,
                                                unsigned short* __restrict__ Wb) {
    int idx = blockIdx.x * 256 + threadIdx.x;  // 14336 = 56*256
    Wb[idx] = f2b(W[idx]);
}

// ---------- hop GEMM: C[n,w] = sum_v X[n,v]*P[w,v], 128x128 bf16 tiles ----------
// z<3: P = P0 + z*1M; z>=3: P = P1 + (z-3)*1M.
// doT: write C row-major [n,w] to Tout+z*tz (used for AT2 build).
// Ht!=null: write Ht c-slices at cc0 = (z<3 ? 32+64z : 64(z-2)).
__global__ __launch_bounds__(256) void k_gemm(const unsigned short* __restrict__ Xb, long xz,
                                              const unsigned short* __restrict__ P0,
                                              const unsigned short* __restrict__ P1,
                                              unsigned short* __restrict__ Tout, long tz,
                                              unsigned short* __restrict__ Ht, int doT) {
    __shared__ union {
        struct { unsigned short xs[8192]; unsigned short ps[8192]; } s;  // 2 planes each
        unsigned short cs[128 * 132];         // [n][v], stride 132 (bank spread)
        unsigned short ct[128 * 136];         // [v][n] for Ht write (34816 B max)
    } lds;
    const int z = blockIdx.z;
    const unsigned short* X = Xb + (size_t)z * (size_t)xz;
    const unsigned short* P = (z < 3) ? P0 + (size_t)z * 1048576u
                                      : P1 + (size_t)(z - 3) * 1048576u;
    const int i0 = blockIdx.x * 128;          // n
    const int j0 = blockIdx.y * 128;          // w
    const int t = threadIdx.x;
    const int lane = t & 63, wave = t >> 6;
    const int l16 = lane & 15, quad = lane >> 4;
    const int wi = (wave >> 1) * 64, wj = (wave & 1) * 64;

    f32x4 acc[4][4] = {};

    const int row = t >> 2, seg = t & 3;
    const unsigned short* xg0 = X + (size_t)(i0 + row) * 1024 + seg * 8;
    const unsigned short* xg1 = xg0 + (size_t)64 * 1024;
    const unsigned short* pg0 = P + (size_t)(j0 + row) * 1024 + seg * 8;
    const unsigned short* pg1 = pg0 + (size_t)64 * 1024;
    unsigned short* lx0 = lds.s.xs + t * 8;          // plane0 rows 0..63
    unsigned short* lp0 = lds.s.ps + t * 8;

    for (int kt = 0; kt < 16; ++kt) {
        const int ko = kt * 64;
        gl2lds16(xg0 + ko,      lx0);
        gl2lds16(xg1 + ko,      lx0 + 2048);         // plane0 rows 64..127
        gl2lds16(xg0 + ko + 32, lx0 + 4096);         // plane1
        gl2lds16(xg1 + ko + 32, lx0 + 6144);
        gl2lds16(pg0 + ko,      lp0);
        gl2lds16(pg1 + ko,      lp0 + 2048);
        gl2lds16(pg0 + ko + 32, lp0 + 4096);
        gl2lds16(pg1 + ko + 32, lp0 + 6144);
        __syncthreads();
#pragma unroll
        for (int p = 0; p < 2; ++p) {
            short8 a[4], b[4];
#pragma unroll
            for (int mi = 0; mi < 4; ++mi)
                a[mi] = *(const short8*)(lds.s.xs + p * 4096 + (wi + mi * 16 + l16) * 32 + quad * 8);
#pragma unroll
            for (int nj = 0; nj < 4; ++nj)
                b[nj] = *(const short8*)(lds.s.ps + p * 4096 + (wj + nj * 16 + l16) * 32 + quad * 8);
#pragma unroll
            for (int mi = 0; mi < 4; ++mi)
#pragma unroll
                for (int nj = 0; nj < 4; ++nj)
                    acc[mi][nj] = __builtin_amdgcn_mfma_f32_16x16x32_bf16(a[mi], b[nj], acc[mi][nj], 0, 0, 0);
        }
        __syncthreads();
    }

    // ---- epilogue A: C row-major [n,w] (AT2 build) ----
    if (doT) {
#pragma unroll
        for (int mi = 0; mi < 4; ++mi)
#pragma unroll
            for (int nj = 0; nj < 4; ++nj)
#pragma unroll
                for (int r = 0; r < 4; ++r)
                    lds.cs[(wi + mi * 16 + quad * 4 + r) * 132 + (wj + nj * 16 + l16)] =
                        f2b(acc[mi][nj][r]);
        __syncthreads();
        unsigned short* O = Tout + (size_t)z * (size_t)tz;
#pragma unroll
        for (int rep = 0; rep < 8; ++rep) {
            int q = rep * 256 + t;            // 2048 16B chunks: 128 rows x 16
            int rr = q >> 4, sg = q & 15;
            *(uint4*)(O + (size_t)(i0 + rr) * 1024 + j0 + sg * 8) =
                *(const uint4*)(lds.cs + rr * 132 + sg * 8);
        }
        __syncthreads();
    }

    // ---- epilogue B: transposed stage [v][n], write Ht c-slices ----
    if (Ht) {
#pragma unroll
        for (int mi = 0; mi < 4; ++mi)
#pragma unroll
            for (int nj = 0; nj < 4; ++nj) {
                ushort4 pk;
                pk.x = f2b(acc[mi][nj][0]);
                pk.y = f2b(acc[mi][nj][1]);
                pk.z = f2b(acc[mi][nj][2]);
                pk.w = f2b(acc[mi][nj][3]);
                *(ushort4*)(lds.ct + (wj + nj * 16 + l16) * 136 + wi + mi * 16 + quad * 4) = pk;
            }
        __syncthreads();
        const int cc0 = (z < 3) ? 32 + 64 * z : 64 * (z - 2);
#pragma unroll
        for (int it = 0; it < 8; ++it) {
            int q = it * 256 + t;             // 2048 16B chunks: 4 slabs x 128 v x 4 seg
            int sg = q & 3, v = (q >> 2) & 127, s = q >> 9;
            int p = (i0 >> 5) + s;            // slab = b*13 + l
            int b = p / 13, l = p - b * 13;
            size_t m = (size_t)b * 13312 + (size_t)(j0 + v) * 13 + l;
            *(uint4*)(Ht + m * 224 + cc0 + sg * 8) =
                *(const uint4*)(lds.ct + v * 136 + s * 32 + sg * 8);
        }
    }
}

// ---------- final conv: y[m,o] = sum_cc Ht[m,cc]*W[o,cc] + bias ----------
// A streamed global->VGPR (zero reuse), W in LDS (pad 232 -> 2-way max),
// per-wave 13 independent 16x64 tiles, 1-deep A prefetch.
__global__ __launch_bounds__(128) void k_fc(const unsigned short* __restrict__ Ht,
                                            const unsigned short* __restrict__ Wb,
                                            const float* __restrict__ bias,
                                            float* __restrict__ y) {
    __shared__ unsigned short sw[64 * 232];
    const int bid = blockIdx.x;               // 1024 = 32 b * 32 vb
    const int b = bid >> 5, v0 = (bid & 31) * 32;
    const int t = threadIdx.x;
    const int lane = t & 63, wave = t >> 6;   // 2 waves
    const int l16 = lane & 15, quad = lane >> 4;

    for (int it = 0; it < 14; ++it) {
        int q = it * 128 + t;                 // 1792 uint4 = 64o x 28sg
        int o = q / 28, sg = q % 28;
        *(uint4*)(sw + o * 232 + sg * 8) = *(const uint4*)(Wb + o * 224 + sg * 8);
    }

    const size_t mw = (size_t)b * 13312 + (size_t)v0 * 13 + wave * 208;
    const unsigned short* ag = Ht + (mw + l16) * 224 + quad * 8;
    float* yb = y + (size_t)b * 851968 + (size_t)v0 * 13 + wave * 208 + quad * 4;

    float bv[4];
#pragma unroll
    for (int nj = 0; nj < 4; ++nj) bv[nj] = bias[nj * 16 + l16];

    short8 cur[7];
#pragma unroll
    for (int kk = 0; kk < 7; ++kk)
        cur[kk] = *(const short8*)(ag + kk * 32);   // mf=0, overlaps W staging
    __syncthreads();

#pragma unroll 1
    for (int mf = 0; mf < 13; ++mf) {
        const int mfn = (mf < 12) ? mf + 1 : 0;     // wrap avoids OOB tail read
        short8 nxt[7];
#pragma unroll
        for (int kk = 0; kk < 7; ++kk)
            nxt[kk] = *(const short8*)(ag + (size_t)mfn * 3584 + kk * 32);
        f32x4 acc[4];
#pragma unroll
        for (int nj = 0; nj < 4; ++nj) acc[nj] = (f32x4){bv[nj], bv[nj], bv[nj], bv[nj]};
#pragma unroll
        for (int kk = 0; kk < 7; ++kk)
#pragma unroll
            for (int nj = 0; nj < 4; ++nj) {
                short8 bf = *(const short8*)(sw + (nj * 16 + l16) * 232 + kk * 32 + quad * 8);
                acc[nj] = __builtin_amdgcn_mfma_f32_16x16x32_bf16(cur[kk], bf, acc[nj], 0, 0, 0);
            }
#pragma unroll
        for (int nj = 0; nj < 4; ++nj)
            *(f32x4*)(yb + (size_t)(nj * 16 + l16) * 13312 + mf * 16) = acc[nj];
#pragma unroll
        for (int kk = 0; kk < 7; ++kk) cur[kk] = nxt[kk];
    }
}

extern "C" void kernel_launch(void* const* d_in, const int* in_sizes, int n_in,
                              void* d_out, int out_size, void* d_ws, size_t ws_size,
                              hipStream_t stream) {
    const float* x    = (const float*)d_in[0];
    const float* A0   = (const float*)d_in[1];
    const float* A1   = (const float*)d_in[2];
    const float* A2   = (const float*)d_in[3];
    const float* W    = (const float*)d_in[4];
    const float* bias = (const float*)d_in[5];

    if (ws_size < WS_NEED) return;

    unsigned short* Ht = (unsigned short*)d_ws;
    unsigned short* AT = (unsigned short*)((char*)d_ws + OFF_AT);
    unsigned short* Wb = (unsigned short*)((char*)d_ws + OFF_WB);
    unsigned short* Tarena = (unsigned short*)d_out;   // block0: x-T
    unsigned short* Abf = Tarena + SZE;                // arena block1 (free)
    unsigned short* AT2 = Tarena + 2 * SZE;            // arena block2 (free)

    k_prep<<<512, 256, 0, stream>>>(x, Tarena, Ht);
    k_prep_A<<<dim3(32, 32, 3), 256, 0, stream>>>(A0, A1, A2, AT, Abf);
    k_prep_W<<<56, 256, 0, stream>>>(W, Wb);
    // AT2[w,v] = sum_u AT[w,u]*Abf[v,u] = (A*A)^T, bf16
    k_gemm<<<dim3(8, 8, 3), 256, 0, stream>>>(AT, 1048576L, Abf, Abf,
                                              AT2, 1048576L, nullptr, 1);
    // all 6 hops from x-T in one launch: z<3 h1 (AT), z>=3 h2 (AT2)
    k_gemm<<<dim3(104, 8, 6), 256, 0, stream>>>(Tarena, 0L, AT, AT2,
                                                nullptr, 0L, Ht, 0);
    k_fc<<<1024, 128, 0, stream>>>(Ht, Wb, bias, (float*)d_out);
}